// Round 1
// baseline (281.945 us; speedup 1.0000x reference)
//
#include <hip/hip_runtime.h>
#include <hip/hip_bf16.h>

// TasteNet fused MLP: z(N,64) -> h1(128) relu -> h2(128) relu -> b(12) ->
// clamp/taste/segment-sum epilogue with x(N,9) -> out(N,3) fp32.
//
// R11 = R10 structure, re-budgeted for 3 waves/SIMD (occupancy attack).
// rocprof R10: MfmaUtil 16.5, VALUBusy 31, HBM 13% peak, Occupancy 18.85 ->
// latency/dependency-stall bound at 2 waves/SIMD. Register peak (~183) was
// the blocker (512/3 = 170 needed). Two liveness cuts:
//  - z prefetch is converted fp32->bf16 right AFTER layer 1 (zv's 32 regs die
//    mid-tile; the 16-reg bz frags carry across the loop instead). A
//    sched_barrier pins the convert before layer 2 so the scheduler can't
//    sink it and re-inflate zv liveness.
//  - bias A-frags are no longer pinned persistent (36 AGPRs freed); rebuilt
//    per tile from LDS. LICM re-hoist is blocked by an opaque runtime zero
//    (asm v_mov) mixed into every bias LDS address.
// zeroC + ones stay pinned (R8 win: no per-chain zero-init VALU).
// Grid 512 -> 768 (3 blocks/CU exactly, LDS 3x53248 = 159744 <= 163840),
// __launch_bounds__(256,3).

typedef __bf16 bf16x8 __attribute__((ext_vector_type(8)));
typedef float  f32x16 __attribute__((ext_vector_type(16)));
typedef unsigned int uint2v __attribute__((ext_vector_type(2)));
typedef unsigned int uint4v __attribute__((ext_vector_type(4)));

#define MFMA32(a, b, c) __builtin_amdgcn_mfma_f32_32x32x16_bf16((a), (b), (c), 0, 0, 0)
// Pin a value into the AGPR half of the unified file (R8 win).
#define PIN_AGPR(v) asm("" : "+a"(v))

// ---- LDS layout (bf16 element offsets), verified R2-R10 ----
#define SW3 0        // 12 rows x 128 elts (row reads m=12..31 overrun into SW1;
                     // garbage feats land in acc3 regs never read)
#define SW1 1536     // 128 rows x 64 elts (128 B row, xor-swizzled 16B chunks)
#define SW2 9728     // 128 rows x 128 elts (256 B row, swizzled)
#define SB1 26112
#define SB2 26240
#define SB3 26368
#define SMEM_ELTS 26384   // 52768 B

#define NBLK    768
#define NTILE   16384          // 524288 rows / 32
#define WSTRIDE (NBLK * 4)     // 3072 waves -> 5 or 6 tiles each

__device__ __forceinline__ unsigned pkbf(float lo, float hi) {
  unsigned short lb = __builtin_bit_cast(unsigned short, (__bf16)lo);
  unsigned short hb = __builtin_bit_cast(unsigned short, (__bf16)hi);
  return ((unsigned)hb << 16) | (unsigned)lb;
}

// 32x32 C-layout -> next-layer B-frag via one permlane32_swap per packed pair.
// Verified R1-R10 (absmax 5.9e-3).
template <int SUB>
__device__ __forceinline__ bf16x8 mk_bfrag(const f32x16 h) {
  constexpr int B = SUB * 8;
  unsigned p01 = pkbf(h[B + 0], h[B + 1]);
  unsigned p23 = pkbf(h[B + 2], h[B + 3]);
  unsigned p45 = pkbf(h[B + 4], h[B + 5]);
  unsigned p67 = pkbf(h[B + 6], h[B + 7]);
  unsigned d0, d1, d2, d3;
#if __has_builtin(__builtin_amdgcn_permlane32_swap)
  uint2v r1 = __builtin_amdgcn_permlane32_swap(p01, p45, false, false);
  uint2v r2 = __builtin_amdgcn_permlane32_swap(p23, p67, false, false);
  d0 = r1[0]; d2 = r1[1];
  d1 = r2[0]; d3 = r2[1];
#else
  int hi = (threadIdx.x >> 5) & 1;
  unsigned sp01 = (unsigned)__shfl_xor((int)p01, 32, 64);
  unsigned sp23 = (unsigned)__shfl_xor((int)p23, 32, 64);
  unsigned sp45 = (unsigned)__shfl_xor((int)p45, 32, 64);
  unsigned sp67 = (unsigned)__shfl_xor((int)p67, 32, 64);
  d0 = hi ? sp45 : p01;
  d2 = hi ? p45  : sp01;
  d1 = hi ? sp67 : p23;
  d3 = hi ? p67  : sp23;
#endif
  uint4v t; t[0] = d0; t[1] = d1; t[2] = d2; t[3] = d3;
  return __builtin_bit_cast(bf16x8, t);
}

// LDS A-frag read: VGPR addr + compile-time immediate byte offset.
__device__ __forceinline__ bf16x8 ldw(const __bf16* sm, int vaddr, int imm) {
  return *(const bf16x8*)((const char*)sm + vaddr + imm);
}

// bias A-frag: A[m][0] = v on q=0 lanes; MFMA'd against ones-B (B[0][:]=1)
__device__ __forceinline__ bf16x8 biasA(__bf16 v) {
  bf16x8 f;
  #pragma unroll
  for (int i = 0; i < 8; ++i) f[i] = (__bf16)0.0f;
  f[0] = v;
  return f;
}

__global__ __launch_bounds__(256, 3)
void tastenet_kernel(const float* __restrict__ x, const float* __restrict__ z,
                     const float* __restrict__ W1, const float* __restrict__ b1,
                     const float* __restrict__ W2, const float* __restrict__ b2,
                     const float* __restrict__ W3, const float* __restrict__ b3,
                     float* __restrict__ out) {
  __shared__ __align__(16) __bf16 sm[SMEM_ELTS];
  const int tid = threadIdx.x;
  unsigned* smw = (unsigned*)sm;

  // ---- stage weights transposed + bf16, xor-swizzled 16B chunks ----
  for (int i = tid; i < 4096; i += 256) {           // W1 (64x128)
    int m = i & 127, k = (i >> 7) * 2;
    smw[SW1 / 2 + m * 32 + (((k >> 3) ^ (m & 7)) << 2) + ((k >> 1) & 3)] =
        pkbf(W1[k * 128 + m], W1[(k + 1) * 128 + m]);
  }
  for (int i = tid; i < 8192; i += 256) {           // W2 (128x128)
    int m = i & 127, k = (i >> 7) * 2;
    smw[SW2 / 2 + m * 64 + (((k >> 3) ^ (m & 7)) << 2) + ((k >> 1) & 3)] =
        pkbf(W2[k * 128 + m], W2[(k + 1) * 128 + m]);
  }
  for (int i = tid; i < 768; i += 256) {            // W3 (128x12)
    int kk = i / 12, m = i - kk * 12, k = kk * 2;
    smw[SW3 / 2 + m * 64 + (((k >> 3) ^ (m & 7)) << 2) + ((k >> 1) & 3)] =
        pkbf(W3[k * 12 + m], W3[(k + 1) * 12 + m]);
  }
  if (tid < 128) { sm[SB1 + tid] = (__bf16)b1[tid]; sm[SB2 + tid] = (__bf16)b2[tid]; }
  if (tid < 12)  sm[SB3 + tid] = (__bf16)b3[tid];
  __syncthreads();

  const int wave = tid >> 6;
  const int lane = tid & 63;
  const int q    = lane >> 5;
  const int n    = lane & 31;
  const int s8   = n & 7;
  const int eq   = q ^ (s8 & 1);
  const int sh   = s8 >> 1;

  // per-lane swizzled A-frag base addresses (8 regs; strides are immediates)
  int aw1[4], aw2[4];
  #pragma unroll
  for (int j = 0; j < 4; ++j) {
    aw1[j] = n * 128 + eq * 16 + 32 * (j ^ sh);   // W1: 128 B rows
    aw2[j] = n * 256 + eq * 16 + 32 * (j ^ sh);   // W2/W3: 256 B rows
  }

  // ---- persistent pinned operands: ones B-frag + zero C (20 AGPRs) ----
  bf16x8 ones;
  #pragma unroll
  for (int i = 0; i < 8; ++i) ones[i] = (__bf16)0.0f;
  if (q == 0) ones[0] = (__bf16)1.0f;
  PIN_AGPR(ones);

  // persistent zero C-operand (AGPR): every MFMA chain starts from this,
  // eliminating per-tile accumulator zero-init VALU work.
  f32x16 zeroC;
  #pragma unroll
  for (int i = 0; i < 16; ++i) zeroC[i] = 0.0f;
  PIN_AGPR(zeroC);

  const int wid = blockIdx.x * 4 + wave;

  // prologue: prefetch + convert z for first tile. bz (16 regs) is the only
  // loop-carried z state; zv (32 regs) is live only loop-top -> post-layer1.
  float4 zv[8];
  bf16x8 bz[4];
  {
    const float* zr = z + ((long)wid * 32 + n) * 64;
    #pragma unroll
    for (int kt = 0; kt < 4; ++kt) {
      zv[2 * kt]     = *(const float4*)(zr + kt * 16 + q * 8);
      zv[2 * kt + 1] = *(const float4*)(zr + kt * 16 + q * 8 + 4);
    }
    #pragma unroll
    for (int kt = 0; kt < 4; ++kt) {
      float4 a = zv[2 * kt], b = zv[2 * kt + 1];
      bf16x8 f;
      f[0] = (__bf16)a.x; f[1] = (__bf16)a.y; f[2] = (__bf16)a.z; f[3] = (__bf16)a.w;
      f[4] = (__bf16)b.x; f[5] = (__bf16)b.y; f[6] = (__bf16)b.z; f[7] = (__bf16)b.w;
      bz[kt] = f;
    }
  }

  #pragma unroll 1
  for (int t = wid; t < NTILE; t += WSTRIDE) {
    const long row = (long)t * 32 + n;

    // opaque runtime zero: folded into bias LDS addresses so LICM cannot
    // hoist the per-tile bias-frag rebuilds into persistent registers.
    int zt;
    asm volatile("v_mov_b32 %0, 0" : "=v"(zt));

    // x for this tile (issued first; done by the mid-tile vmcnt wait).
    const float* xr = x + row * 9;
    float xv0 = xr[q * 4 + 0], xv1 = xr[q * 4 + 1];
    float xv2 = xr[q * 4 + 2], xv3 = xr[q * 4 + 3];
    float xv4 = xr[8];

    // prefetch next tile's z (consumed by the post-layer1 convert).
    if (t + WSTRIDE < NTILE) {
      const float* zr = z + ((long)(t + WSTRIDE) * 32 + n) * 64;
      #pragma unroll
      for (int kt = 0; kt < 4; ++kt) {
        zv[2 * kt]     = *(const float4*)(zr + kt * 16 + q * 8);
        zv[2 * kt + 1] = *(const float4*)(zr + kt * 16 + q * 8 + 4);
      }
    }

    // ---- layer 1: bias-start chains (bias frags rebuilt per tile) ----
    bf16x8 bf2[8];
    #pragma unroll
    for (int fp = 0; fp < 2; ++fp) {
      f32x16 aA = MFMA32(
          biasA((q == 0) ? sm[SB1 + zt + (2 * fp + 0) * 32 + n] : (__bf16)0.0f),
          ones, zeroC);
      f32x16 aB = MFMA32(
          biasA((q == 0) ? sm[SB1 + zt + (2 * fp + 1) * 32 + n] : (__bf16)0.0f),
          ones, zeroC);
      PIN_AGPR(aA); PIN_AGPR(aB);
      #pragma unroll
      for (int kt = 0; kt < 4; ++kt) {
        aA = MFMA32(ldw(sm, aw1[kt], SW1 * 2 + (2 * fp + 0) * 4096), bz[kt], aA);
        aB = MFMA32(ldw(sm, aw1[kt], SW1 * 2 + (2 * fp + 1) * 4096), bz[kt], aB);
      }
      #pragma unroll
      for (int i = 0; i < 16; ++i) { aA[i] = fmaxf(aA[i], 0.0f); aB[i] = fmaxf(aB[i], 0.0f); }
      bf2[4 * fp + 0] = mk_bfrag<0>(aA);
      bf2[4 * fp + 1] = mk_bfrag<1>(aA);
      bf2[4 * fp + 2] = mk_bfrag<0>(aB);
      bf2[4 * fp + 3] = mk_bfrag<1>(aB);
    }

    // ---- convert next tile's z NOW: zv (32 regs) dies, bz (16) reborn.
    // sched_barrier pins this before layer 2 so the scheduler can't sink it
    // (which would keep zv live through layer 2 and blow the 3-wave budget).
    if (t + WSTRIDE < NTILE) {
      #pragma unroll
      for (int kt = 0; kt < 4; ++kt) {
        float4 a = zv[2 * kt], b = zv[2 * kt + 1];
        bf16x8 f;
        f[0] = (__bf16)a.x; f[1] = (__bf16)a.y; f[2] = (__bf16)a.z; f[3] = (__bf16)a.w;
        f[4] = (__bf16)b.x; f[5] = (__bf16)b.y; f[6] = (__bf16)b.z; f[7] = (__bf16)b.w;
        bz[kt] = f;
      }
    }
    __builtin_amdgcn_sched_barrier(0);

    // ---- layer 2 (bias-start chains) with layer 3 fused ----
    f32x16 acc3 = MFMA32(
        biasA((q == 0 && n < 12) ? sm[SB3 + zt + n] : (__bf16)0.0f), ones, zeroC);
    PIN_AGPR(acc3);
    #pragma unroll
    for (int fp = 0; fp < 2; ++fp) {
      f32x16 aA = MFMA32(
          biasA((q == 0) ? sm[SB2 + zt + (2 * fp + 0) * 32 + n] : (__bf16)0.0f),
          ones, zeroC);
      f32x16 aB = MFMA32(
          biasA((q == 0) ? sm[SB2 + zt + (2 * fp + 1) * 32 + n] : (__bf16)0.0f),
          ones, zeroC);
      PIN_AGPR(aA); PIN_AGPR(aB);
      #pragma unroll
      for (int kt = 0; kt < 8; ++kt) {
        aA = MFMA32(ldw(sm, aw2[kt & 3], SW2 * 2 + (2 * fp + 0) * 8192 + 128 * (kt >> 2)),
                    bf2[kt], aA);
        aB = MFMA32(ldw(sm, aw2[kt & 3], SW2 * 2 + (2 * fp + 1) * 8192 + 128 * (kt >> 2)),
                    bf2[kt], aB);
      }
      #pragma unroll
      for (int i = 0; i < 16; ++i) { aA[i] = fmaxf(aA[i], 0.0f); aB[i] = fmaxf(aB[i], 0.0f); }
      // h2 features 64*fp + [0,64) == layer-3 K block kt = 4*fp + [0,4)
      acc3 = MFMA32(ldw(sm, aw2[0], SW3 * 2 + 128 * fp), mk_bfrag<0>(aA), acc3);
      acc3 = MFMA32(ldw(sm, aw2[1], SW3 * 2 + 128 * fp), mk_bfrag<1>(aA), acc3);
      acc3 = MFMA32(ldw(sm, aw2[2], SW3 * 2 + 128 * fp), mk_bfrag<0>(aB), acc3);
      acc3 = MFMA32(ldw(sm, aw2[3], SW3 * 2 + 128 * fp), mk_bfrag<1>(aB), acc3);
    }

    // ---- epilogue (only regs 0..7 carry real features) ----
    float t0 = acc3[0], t1 = acc3[1], t2 = acc3[2], t3 = acc3[3];
    float t4 = acc3[4], t5 = acc3[5], t6 = acc3[6], t7 = acc3[7];
    float o0 = 0.f, o1 = 0.f, o2 = 0.f, g1v = 0.f, g2v = 0.f;
    if (q == 0) {
      t0 = fminf(t0, 0.0f); t1 = fminf(t1, 0.0f);
      t2 = fminf(t2, 0.0f); t3 = fminf(t3, 0.0f);
      t4 = fminf(t4, 0.0f);                       // feat 8
      o0 = xv0 * t0 + xv1 * t1 + xv2 * t2 + t5;   // seg0 + I9
      o1 = xv3 * t3 + t6;                         // seg1 part + I10
      o2 = xv4 * t4 + t7;                         // seg2 part + I11
    } else {
      t0 = fminf(t0, 0.0f); t1 = fminf(t1, 0.0f); // feats 4,5
      t3 = fminf(t3, 0.0f);                       // feat 7 (feat 6 passes)
      g1v = xv0 * t0 + xv1 * t1;
      g2v = xv2 * t2 + xv3 * t3;
    }
    float a1v = __shfl_xor(g1v, 32, 64);
    float a2v = __shfl_xor(g2v, 32, 64);
    if (q == 0) {
      float* op = out + row * 3;
      op[0] = o0;
      op[1] = o1 + a1v;
      op[2] = o2 + a2v;
    }
  }
}

extern "C" void kernel_launch(void* const* d_in, const int* in_sizes, int n_in,
                              void* d_out, int out_size, void* d_ws, size_t ws_size,
                              hipStream_t stream) {
  const float* x  = (const float*)d_in[0];
  const float* z  = (const float*)d_in[1];
  const float* W1 = (const float*)d_in[2];
  const float* b1 = (const float*)d_in[3];
  const float* W2 = (const float*)d_in[4];
  const float* b2 = (const float*)d_in[5];
  const float* W3 = (const float*)d_in[6];
  const float* b3 = (const float*)d_in[7];
  tastenet_kernel<<<dim3(NBLK), dim3(256), 0, stream>>>(
      x, z, W1, b1, W2, b2, W3, b3, (float*)d_out);
}

// Round 3
// 247.630 us; speedup vs baseline: 1.1386x; 1.1386x over previous
//
#include <hip/hip_runtime.h>
#include <hip/hip_bf16.h>

// TasteNet fused MLP: z(N,64) -> h1(128) relu -> h2(128) relu -> b(12) ->
// clamp/taste/segment-sum epilogue with x(N,9) -> out(N,3) fp32.
//
// R13 = R12 resubmitted verbatim (R12 bench was a GPUAcquisitionTimeout —
// no data). Theory unchanged:
// R12 = back to the 2-wave regime (R11's 3-wave attempt spilled: arch/AGPR
// split 84/84, arch side needed ~105 -> 133 MB scratch writes). R10 had
// ~64 unified regs of headroom at 2 waves; spend it on MFMA ILP instead:
//  - layer 1: 4 independent chains (was 2x2 sequential fp-pairs)
//  - layer 2: 4 independent chains
//  - layer 3: acc3 split into two 4-deep chains, merged in epilogue
//    (was one 9-deep serial chain)
// Keeps R11's verified liveness trick: z fp32->bf16 convert happens right
// after layer 1 (zv's 32 regs dead during L2; 16-reg bz carries the loop),
// sched_barrier pins the convert. Biases re-pinned persistent (R10 win).
// Budget at L2 peak ~230 <= 256 -> 2 waves/SIMD preserved, no spill.

typedef __bf16 bf16x8 __attribute__((ext_vector_type(8)));
typedef float  f32x16 __attribute__((ext_vector_type(16)));
typedef unsigned int uint2v __attribute__((ext_vector_type(2)));
typedef unsigned int uint4v __attribute__((ext_vector_type(4)));

#define MFMA32(a, b, c) __builtin_amdgcn_mfma_f32_32x32x16_bf16((a), (b), (c), 0, 0, 0)
// Pin a value into the AGPR half of the unified file (R8 win).
#define PIN_AGPR(v) asm("" : "+a"(v))

// ---- LDS layout (bf16 element offsets), verified R2-R11 ----
#define SW3 0        // 12 rows x 128 elts (row reads m=12..31 overrun into SW1;
                     // garbage feats land in acc regs never read)
#define SW1 1536     // 128 rows x 64 elts (128 B row, xor-swizzled 16B chunks)
#define SW2 9728     // 128 rows x 128 elts (256 B row, swizzled)
#define SB1 26112
#define SB2 26240
#define SB3 26368
#define SMEM_ELTS 26384   // 52768 B

#define NBLK    512
#define NTILE   16384          // 524288 rows / 32
#define WSTRIDE (NBLK * 4)     // 2048 waves -> exactly 8 tiles each

__device__ __forceinline__ unsigned pkbf(float lo, float hi) {
  unsigned short lb = __builtin_bit_cast(unsigned short, (__bf16)lo);
  unsigned short hb = __builtin_bit_cast(unsigned short, (__bf16)hi);
  return ((unsigned)hb << 16) | (unsigned)lb;
}

// 32x32 C-layout -> next-layer B-frag via one permlane32_swap per packed pair.
// Verified R1-R11 (absmax 5.9e-3).
template <int SUB>
__device__ __forceinline__ bf16x8 mk_bfrag(const f32x16 h) {
  constexpr int B = SUB * 8;
  unsigned p01 = pkbf(h[B + 0], h[B + 1]);
  unsigned p23 = pkbf(h[B + 2], h[B + 3]);
  unsigned p45 = pkbf(h[B + 4], h[B + 5]);
  unsigned p67 = pkbf(h[B + 6], h[B + 7]);
  unsigned d0, d1, d2, d3;
#if __has_builtin(__builtin_amdgcn_permlane32_swap)
  uint2v r1 = __builtin_amdgcn_permlane32_swap(p01, p45, false, false);
  uint2v r2 = __builtin_amdgcn_permlane32_swap(p23, p67, false, false);
  d0 = r1[0]; d2 = r1[1];
  d1 = r2[0]; d3 = r2[1];
#else
  int hi = (threadIdx.x >> 5) & 1;
  unsigned sp01 = (unsigned)__shfl_xor((int)p01, 32, 64);
  unsigned sp23 = (unsigned)__shfl_xor((int)p23, 32, 64);
  unsigned sp45 = (unsigned)__shfl_xor((int)p45, 32, 64);
  unsigned sp67 = (unsigned)__shfl_xor((int)p67, 32, 64);
  d0 = hi ? sp45 : p01;
  d2 = hi ? p45  : sp01;
  d1 = hi ? sp67 : p23;
  d3 = hi ? p67  : sp23;
#endif
  uint4v t; t[0] = d0; t[1] = d1; t[2] = d2; t[3] = d3;
  return __builtin_bit_cast(bf16x8, t);
}

// LDS A-frag read: VGPR addr + compile-time immediate byte offset.
__device__ __forceinline__ bf16x8 ldw(const __bf16* sm, int vaddr, int imm) {
  return *(const bf16x8*)((const char*)sm + vaddr + imm);
}

// bias A-frag: A[m][0] = v on q=0 lanes; MFMA'd against ones-B (B[0][:]=1)
__device__ __forceinline__ bf16x8 biasA(__bf16 v) {
  bf16x8 f;
  #pragma unroll
  for (int i = 0; i < 8; ++i) f[i] = (__bf16)0.0f;
  f[0] = v;
  return f;
}

__global__ __launch_bounds__(256, 2)
void tastenet_kernel(const float* __restrict__ x, const float* __restrict__ z,
                     const float* __restrict__ W1, const float* __restrict__ b1,
                     const float* __restrict__ W2, const float* __restrict__ b2,
                     const float* __restrict__ W3, const float* __restrict__ b3,
                     float* __restrict__ out) {
  __shared__ __align__(16) __bf16 sm[SMEM_ELTS];
  const int tid = threadIdx.x;
  unsigned* smw = (unsigned*)sm;

  // ---- stage weights transposed + bf16, xor-swizzled 16B chunks ----
  for (int i = tid; i < 4096; i += 256) {           // W1 (64x128)
    int m = i & 127, k = (i >> 7) * 2;
    smw[SW1 / 2 + m * 32 + (((k >> 3) ^ (m & 7)) << 2) + ((k >> 1) & 3)] =
        pkbf(W1[k * 128 + m], W1[(k + 1) * 128 + m]);
  }
  for (int i = tid; i < 8192; i += 256) {           // W2 (128x128)
    int m = i & 127, k = (i >> 7) * 2;
    smw[SW2 / 2 + m * 64 + (((k >> 3) ^ (m & 7)) << 2) + ((k >> 1) & 3)] =
        pkbf(W2[k * 128 + m], W2[(k + 1) * 128 + m]);
  }
  for (int i = tid; i < 768; i += 256) {            // W3 (128x12)
    int kk = i / 12, m = i - kk * 12, k = kk * 2;
    smw[SW3 / 2 + m * 64 + (((k >> 3) ^ (m & 7)) << 2) + ((k >> 1) & 3)] =
        pkbf(W3[k * 12 + m], W3[(k + 1) * 12 + m]);
  }
  if (tid < 128) { sm[SB1 + tid] = (__bf16)b1[tid]; sm[SB2 + tid] = (__bf16)b2[tid]; }
  if (tid < 12)  sm[SB3 + tid] = (__bf16)b3[tid];
  __syncthreads();

  const int wave = tid >> 6;
  const int lane = tid & 63;
  const int q    = lane >> 5;
  const int n    = lane & 31;
  const int s8   = n & 7;
  const int eq   = q ^ (s8 & 1);
  const int sh   = s8 >> 1;

  // per-lane swizzled A-frag base addresses (8 regs; strides are immediates)
  int aw1[4], aw2[4];
  #pragma unroll
  for (int j = 0; j < 4; ++j) {
    aw1[j] = n * 128 + eq * 16 + 32 * (j ^ sh);   // W1: 128 B rows
    aw2[j] = n * 256 + eq * 16 + 32 * (j ^ sh);   // W2/W3: 256 B rows
  }

  // ---- persistent operand fragments, all pinned to the AGPR half ----
  bf16x8 ones;
  #pragma unroll
  for (int i = 0; i < 8; ++i) ones[i] = (__bf16)0.0f;
  if (q == 0) ones[0] = (__bf16)1.0f;
  PIN_AGPR(ones);

  bf16x8 ba1[4], ba2[4], ba3;
  #pragma unroll
  for (int f = 0; f < 4; ++f) {
    ba1[f] = biasA((q == 0) ? sm[SB1 + f * 32 + n] : (__bf16)0.0f);
    ba2[f] = biasA((q == 0) ? sm[SB2 + f * 32 + n] : (__bf16)0.0f);
    PIN_AGPR(ba1[f]); PIN_AGPR(ba2[f]);
  }
  ba3 = biasA((q == 0 && n < 12) ? sm[SB3 + n] : (__bf16)0.0f);
  PIN_AGPR(ba3);

  // persistent zero C-operand (AGPR): every MFMA chain starts from this,
  // eliminating per-tile accumulator zero-init VALU work.
  f32x16 zeroC;
  #pragma unroll
  for (int i = 0; i < 16; ++i) zeroC[i] = 0.0f;
  PIN_AGPR(zeroC);

  const int wid = blockIdx.x * 4 + wave;

  // prologue: prefetch + convert z for first tile. bz (16 regs) is the only
  // loop-carried z state; zv (32 regs) is live only loop-top -> post-layer1.
  float4 zv[8];
  bf16x8 bz[4];
  {
    const float* zr = z + ((long)wid * 32 + n) * 64;
    #pragma unroll
    for (int kt = 0; kt < 4; ++kt) {
      zv[2 * kt]     = *(const float4*)(zr + kt * 16 + q * 8);
      zv[2 * kt + 1] = *(const float4*)(zr + kt * 16 + q * 8 + 4);
    }
    #pragma unroll
    for (int kt = 0; kt < 4; ++kt) {
      float4 a = zv[2 * kt], b = zv[2 * kt + 1];
      bf16x8 f;
      f[0] = (__bf16)a.x; f[1] = (__bf16)a.y; f[2] = (__bf16)a.z; f[3] = (__bf16)a.w;
      f[4] = (__bf16)b.x; f[5] = (__bf16)b.y; f[6] = (__bf16)b.z; f[7] = (__bf16)b.w;
      bz[kt] = f;
    }
  }

  #pragma unroll 1
  for (int t = wid; t < NTILE; t += WSTRIDE) {
    const long row = (long)t * 32 + n;

    // x for this tile (issued first; done by the mid-tile vmcnt wait).
    const float* xr = x + row * 9;
    float xv0 = xr[q * 4 + 0], xv1 = xr[q * 4 + 1];
    float xv2 = xr[q * 4 + 2], xv3 = xr[q * 4 + 3];
    float xv4 = xr[8];

    // prefetch next tile's z (consumed by the post-layer1 convert).
    if (t + WSTRIDE < NTILE) {
      const float* zr = z + ((long)(t + WSTRIDE) * 32 + n) * 64;
      #pragma unroll
      for (int kt = 0; kt < 4; ++kt) {
        zv[2 * kt]     = *(const float4*)(zr + kt * 16 + q * 8);
        zv[2 * kt + 1] = *(const float4*)(zr + kt * 16 + q * 8 + 4);
      }
    }

    // ---- layer 1: 4 independent bias-start chains (4-way MFMA ILP) ----
    f32x16 d0 = MFMA32(ba1[0], ones, zeroC);
    f32x16 d1 = MFMA32(ba1[1], ones, zeroC);
    f32x16 d2 = MFMA32(ba1[2], ones, zeroC);
    f32x16 d3 = MFMA32(ba1[3], ones, zeroC);
    PIN_AGPR(d0); PIN_AGPR(d1); PIN_AGPR(d2); PIN_AGPR(d3);
    #pragma unroll
    for (int kt = 0; kt < 4; ++kt) {
      d0 = MFMA32(ldw(sm, aw1[kt], SW1 * 2 + 0 * 4096), bz[kt], d0);
      d1 = MFMA32(ldw(sm, aw1[kt], SW1 * 2 + 1 * 4096), bz[kt], d1);
      d2 = MFMA32(ldw(sm, aw1[kt], SW1 * 2 + 2 * 4096), bz[kt], d2);
      d3 = MFMA32(ldw(sm, aw1[kt], SW1 * 2 + 3 * 4096), bz[kt], d3);
    }
    #pragma unroll
    for (int i = 0; i < 16; ++i) {
      d0[i] = fmaxf(d0[i], 0.0f); d1[i] = fmaxf(d1[i], 0.0f);
      d2[i] = fmaxf(d2[i], 0.0f); d3[i] = fmaxf(d3[i], 0.0f);
    }
    bf16x8 bf2[8];
    bf2[0] = mk_bfrag<0>(d0); bf2[1] = mk_bfrag<1>(d0);
    bf2[2] = mk_bfrag<0>(d1); bf2[3] = mk_bfrag<1>(d1);
    bf2[4] = mk_bfrag<0>(d2); bf2[5] = mk_bfrag<1>(d2);
    bf2[6] = mk_bfrag<0>(d3); bf2[7] = mk_bfrag<1>(d3);

    // ---- convert next tile's z NOW: zv (32 regs) dies, bz (16) reborn.
    // sched_barrier pins this before layer 2 so the scheduler can't sink it
    // (which would keep zv live through layer 2 and blow the 2-wave budget).
    if (t + WSTRIDE < NTILE) {
      #pragma unroll
      for (int kt = 0; kt < 4; ++kt) {
        float4 a = zv[2 * kt], b = zv[2 * kt + 1];
        bf16x8 f;
        f[0] = (__bf16)a.x; f[1] = (__bf16)a.y; f[2] = (__bf16)a.z; f[3] = (__bf16)a.w;
        f[4] = (__bf16)b.x; f[5] = (__bf16)b.y; f[6] = (__bf16)b.z; f[7] = (__bf16)b.w;
        bz[kt] = f;
      }
    }
    __builtin_amdgcn_sched_barrier(0);

    // ---- layer 2: 4 independent bias-start chains, K=128 ----
    f32x16 c0 = MFMA32(ba2[0], ones, zeroC);
    f32x16 c1 = MFMA32(ba2[1], ones, zeroC);
    f32x16 c2 = MFMA32(ba2[2], ones, zeroC);
    f32x16 c3 = MFMA32(ba2[3], ones, zeroC);
    PIN_AGPR(c0); PIN_AGPR(c1); PIN_AGPR(c2); PIN_AGPR(c3);
    #pragma unroll
    for (int kt = 0; kt < 8; ++kt) {
      const int ro = 128 * (kt >> 2);
      c0 = MFMA32(ldw(sm, aw2[kt & 3], SW2 * 2 + 0 * 8192 + ro), bf2[kt], c0);
      c1 = MFMA32(ldw(sm, aw2[kt & 3], SW2 * 2 + 1 * 8192 + ro), bf2[kt], c1);
      c2 = MFMA32(ldw(sm, aw2[kt & 3], SW2 * 2 + 2 * 8192 + ro), bf2[kt], c2);
      c3 = MFMA32(ldw(sm, aw2[kt & 3], SW2 * 2 + 3 * 8192 + ro), bf2[kt], c3);
    }
    #pragma unroll
    for (int i = 0; i < 16; ++i) {
      c0[i] = fmaxf(c0[i], 0.0f); c1[i] = fmaxf(c1[i], 0.0f);
      c2[i] = fmaxf(c2[i], 0.0f); c3[i] = fmaxf(c3[i], 0.0f);
    }

    // ---- layer 3: two independent 4-deep chains (was one 9-deep) ----
    // h2 feature blocks: c0->[0,32) c1->[32,64) c2->[64,96) c3->[96,128)
    // L3 K rows [0,64) read SW3+0 via aw2[0..3]; rows [64,128) read SW3+128.
    f32x16 a3a = MFMA32(ba3, ones, zeroC);
    PIN_AGPR(a3a);
    a3a = MFMA32(ldw(sm, aw2[0], SW3 * 2 + 0),   mk_bfrag<0>(c0), a3a);
    f32x16 a3b = MFMA32(ldw(sm, aw2[0], SW3 * 2 + 128), mk_bfrag<0>(c2), zeroC);
    PIN_AGPR(a3b);
    a3a = MFMA32(ldw(sm, aw2[1], SW3 * 2 + 0),   mk_bfrag<1>(c0), a3a);
    a3b = MFMA32(ldw(sm, aw2[1], SW3 * 2 + 128), mk_bfrag<1>(c2), a3b);
    a3a = MFMA32(ldw(sm, aw2[2], SW3 * 2 + 0),   mk_bfrag<0>(c1), a3a);
    a3b = MFMA32(ldw(sm, aw2[2], SW3 * 2 + 128), mk_bfrag<0>(c3), a3b);
    a3a = MFMA32(ldw(sm, aw2[3], SW3 * 2 + 0),   mk_bfrag<1>(c1), a3a);
    a3b = MFMA32(ldw(sm, aw2[3], SW3 * 2 + 128), mk_bfrag<1>(c3), a3b);

    // ---- epilogue (only regs 0..7 carry real features) ----
    float t0 = a3a[0] + a3b[0], t1 = a3a[1] + a3b[1];
    float t2 = a3a[2] + a3b[2], t3 = a3a[3] + a3b[3];
    float t4 = a3a[4] + a3b[4], t5 = a3a[5] + a3b[5];
    float t6 = a3a[6] + a3b[6], t7 = a3a[7] + a3b[7];
    float o0 = 0.f, o1 = 0.f, o2 = 0.f, g1v = 0.f, g2v = 0.f;
    if (q == 0) {
      t0 = fminf(t0, 0.0f); t1 = fminf(t1, 0.0f);
      t2 = fminf(t2, 0.0f); t3 = fminf(t3, 0.0f);
      t4 = fminf(t4, 0.0f);                       // feat 8
      o0 = xv0 * t0 + xv1 * t1 + xv2 * t2 + t5;   // seg0 + I9
      o1 = xv3 * t3 + t6;                         // seg1 part + I10
      o2 = xv4 * t4 + t7;                         // seg2 part + I11
    } else {
      t0 = fminf(t0, 0.0f); t1 = fminf(t1, 0.0f); // feats 4,5
      t3 = fminf(t3, 0.0f);                       // feat 7 (feat 6 passes)
      g1v = xv0 * t0 + xv1 * t1;
      g2v = xv2 * t2 + xv3 * t3;
    }
    float a1v = __shfl_xor(g1v, 32, 64);
    float a2v = __shfl_xor(g2v, 32, 64);
    if (q == 0) {
      float* op = out + row * 3;
      op[0] = o0;
      op[1] = o1 + a1v;
      op[2] = o2 + a2v;
    }
  }
}

extern "C" void kernel_launch(void* const* d_in, const int* in_sizes, int n_in,
                              void* d_out, int out_size, void* d_ws, size_t ws_size,
                              hipStream_t stream) {
  const float* x  = (const float*)d_in[0];
  const float* z  = (const float*)d_in[1];
  const float* W1 = (const float*)d_in[2];
  const float* b1 = (const float*)d_in[3];
  const float* W2 = (const float*)d_in[4];
  const float* b2 = (const float*)d_in[5];
  const float* W3 = (const float*)d_in[6];
  const float* b3 = (const float*)d_in[7];
  tastenet_kernel<<<dim3(NBLK), dim3(256), 0, stream>>>(
      x, z, W1, b1, W2, b2, W3, b3, (float*)d_out);
}

// Round 7
// 241.135 us; speedup vs baseline: 1.1692x; 1.0269x over previous
//
#include <hip/hip_runtime.h>
#include <hip/hip_bf16.h>

// TasteNet fused MLP: z(N,64) -> h1(128) relu -> h2(128) relu -> b(12) ->
// clamp/taste/segment-sum epilogue with x(N,9) -> out(N,3) fp32.
//
// R17 = R14/R15/R16 resubmitted verbatim (three consecutive
// GPUAcquisitionTimeout broker failures — this design has never run).
// Theory unchanged:
// R14: arch-register-pressure attack. R10 sat at the arch cliff (VGPR 128 +
// spill); R11/R13 proved adding state regresses in proportion to spill. The
// stall is no-scheduling-slack: ds_read_b128 weight loads can't be hoisted,
// serializing ~120cy LDS latency per MFMA chain step.
//  - z prefetch ring moved from 32 VGPRs to LDS via global_load_lds (16B/lane,
//    zero VGPR cost). Wave-private 8 KB slot, single-slot read-then-refill.
//  - 512-thread blocks (8 waves), grid 256, 1 block/CU: weights staged once
//    per 8 waves; LDS = 52768 + 8*8192 = 118304 B. Occupancy unchanged
//    (8 waves/CU = 2/SIMD), reg budget unchanged (256/wave).
//  - z pre-swizzled on the GLOBAL address (chunk ^= row&15) so the linear
//    LDS write gives an 8-way (not 32-way) bank-conflict read-back.
//  - load order: vmcnt(0) [drains z(t), full-tile cover] -> z ds_read/cvt ->
//    x issue -> SB -> gll(t+1) -> SB -> compute. x older than gll in the
//    vmem queue, so the epilogue x-wait leaves the prefetch outstanding.
// Compute structure = R10 verbatim (best measured: 83.4 us).

typedef __bf16 bf16x8 __attribute__((ext_vector_type(8)));
typedef float  f32x16 __attribute__((ext_vector_type(16)));
typedef unsigned int uint2v __attribute__((ext_vector_type(2)));
typedef unsigned int uint4v __attribute__((ext_vector_type(4)));

#define MFMA32(a, b, c) __builtin_amdgcn_mfma_f32_32x32x16_bf16((a), (b), (c), 0, 0, 0)
// Pin a value into the AGPR half of the unified file (R8 win).
#define PIN_AGPR(v) asm("" : "+a"(v))

// ---- LDS layout (bf16 element offsets), weights verified R2-R13 ----
#define SW3 0        // 12 rows x 128 elts (row reads m=12..31 overrun into SW1;
                     // garbage feats land in acc regs never read)
#define SW1 1536     // 128 rows x 64 elts (128 B row, xor-swizzled 16B chunks)
#define SW2 9728     // 128 rows x 128 elts (256 B row, swizzled)
#define SB1 26112
#define SB2 26240
#define SB3 26368
#define ZS_BYTE 52768              // z slots: 8 waves x 8192 B
#define SMEM_ELTS (26384 + 32768)  // 118304 B total

#define NBLK    256
#define NTHR    512
#define NTILE   16384          // 524288 rows / 32
#define WSTRIDE (NBLK * 8)     // 2048 waves -> exactly 8 tiles each

typedef __attribute__((address_space(3))) unsigned int lds_u32;
typedef __attribute__((address_space(1))) const unsigned int glb_u32;

// async 16B/lane global->LDS: dest = uniform base + lane*16 (linear).
__device__ __forceinline__ void gll16(const float* g, const void* l) {
  __builtin_amdgcn_global_load_lds((glb_u32*)g, (lds_u32*)l, 16, 0, 0);
}

__device__ __forceinline__ unsigned pkbf(float lo, float hi) {
  unsigned short lb = __builtin_bit_cast(unsigned short, (__bf16)lo);
  unsigned short hb = __builtin_bit_cast(unsigned short, (__bf16)hi);
  return ((unsigned)hb << 16) | (unsigned)lb;
}

// 32x32 C-layout -> next-layer B-frag via one permlane32_swap per packed pair.
// Verified R1-R13 (absmax 5.9e-3).
template <int SUB>
__device__ __forceinline__ bf16x8 mk_bfrag(const f32x16 h) {
  constexpr int B = SUB * 8;
  unsigned p01 = pkbf(h[B + 0], h[B + 1]);
  unsigned p23 = pkbf(h[B + 2], h[B + 3]);
  unsigned p45 = pkbf(h[B + 4], h[B + 5]);
  unsigned p67 = pkbf(h[B + 6], h[B + 7]);
  unsigned d0, d1, d2, d3;
#if __has_builtin(__builtin_amdgcn_permlane32_swap)
  uint2v r1 = __builtin_amdgcn_permlane32_swap(p01, p45, false, false);
  uint2v r2 = __builtin_amdgcn_permlane32_swap(p23, p67, false, false);
  d0 = r1[0]; d2 = r1[1];
  d1 = r2[0]; d3 = r2[1];
#else
  int hi = (threadIdx.x >> 5) & 1;
  unsigned sp01 = (unsigned)__shfl_xor((int)p01, 32, 64);
  unsigned sp23 = (unsigned)__shfl_xor((int)p23, 32, 64);
  unsigned sp45 = (unsigned)__shfl_xor((int)p45, 32, 64);
  unsigned sp67 = (unsigned)__shfl_xor((int)p67, 32, 64);
  d0 = hi ? sp45 : p01;
  d2 = hi ? p45  : sp01;
  d1 = hi ? sp67 : p23;
  d3 = hi ? p67  : sp23;
#endif
  uint4v t; t[0] = d0; t[1] = d1; t[2] = d2; t[3] = d3;
  return __builtin_bit_cast(bf16x8, t);
}

// LDS A-frag read: VGPR addr + compile-time immediate byte offset.
__device__ __forceinline__ bf16x8 ldw(const __bf16* sm, int vaddr, int imm) {
  return *(const bf16x8*)((const char*)sm + vaddr + imm);
}

// LDS z read: 16B at a precomputed swizzled byte offset.
__device__ __forceinline__ float4 ldz(const __bf16* sm, int vaddr) {
  return *(const float4*)((const char*)sm + vaddr);
}

// bias A-frag: A[m][0] = v on q=0 lanes; MFMA'd against ones-B (B[0][:]=1)
__device__ __forceinline__ bf16x8 biasA(__bf16 v) {
  bf16x8 f;
  #pragma unroll
  for (int i = 0; i < 8; ++i) f[i] = (__bf16)0.0f;
  f[0] = v;
  return f;
}

__global__ __launch_bounds__(512, 2)
void tastenet_kernel(const float* __restrict__ x, const float* __restrict__ z,
                     const float* __restrict__ W1, const float* __restrict__ b1,
                     const float* __restrict__ W2, const float* __restrict__ b2,
                     const float* __restrict__ W3, const float* __restrict__ b3,
                     float* __restrict__ out) {
  __shared__ __align__(16) __bf16 sm[SMEM_ELTS];
  const int tid = threadIdx.x;
  unsigned* smw = (unsigned*)sm;

  // ---- stage weights transposed + bf16, xor-swizzled 16B chunks ----
  for (int i = tid; i < 4096; i += NTHR) {          // W1 (64x128)
    int m = i & 127, k = (i >> 7) * 2;
    smw[SW1 / 2 + m * 32 + (((k >> 3) ^ (m & 7)) << 2) + ((k >> 1) & 3)] =
        pkbf(W1[k * 128 + m], W1[(k + 1) * 128 + m]);
  }
  for (int i = tid; i < 8192; i += NTHR) {          // W2 (128x128)
    int m = i & 127, k = (i >> 7) * 2;
    smw[SW2 / 2 + m * 64 + (((k >> 3) ^ (m & 7)) << 2) + ((k >> 1) & 3)] =
        pkbf(W2[k * 128 + m], W2[(k + 1) * 128 + m]);
  }
  for (int i = tid; i < 768; i += NTHR) {           // W3 (128x12)
    int kk = i / 12, m = i - kk * 12, k = kk * 2;
    smw[SW3 / 2 + m * 64 + (((k >> 3) ^ (m & 7)) << 2) + ((k >> 1) & 3)] =
        pkbf(W3[k * 12 + m], W3[(k + 1) * 12 + m]);
  }
  if (tid < 128) { sm[SB1 + tid] = (__bf16)b1[tid]; sm[SB2 + tid] = (__bf16)b2[tid]; }
  if (tid < 12)  sm[SB3 + tid] = (__bf16)b3[tid];
  __syncthreads();

  const int wave = tid >> 6;           // 0..7
  const int lane = tid & 63;
  const int q    = lane >> 5;
  const int n    = lane & 31;
  const int s8   = n & 7;
  const int eq   = q ^ (s8 & 1);
  const int sh   = s8 >> 1;

  // per-lane swizzled A-frag base addresses (8 regs; strides are immediates)
  int aw1[4], aw2[4];
  #pragma unroll
  for (int j = 0; j < 4; ++j) {
    aw1[j] = n * 128 + eq * 16 + 32 * (j ^ sh);   // W1: 128 B rows
    aw2[j] = n * 256 + eq * 16 + 32 * (j ^ sh);   // W2/W3: 256 B rows
  }

  // ---- z slot addressing ----
  // write side (global pre-swizzle): inst i, lane l -> row r=4i+(l>>4),
  // LDS chunk c'=l&15 holds global chunk g = c' ^ (r&15). Linear LDS dest.
  const char* slotp = (const char*)sm + ZS_BYTE + wave * 8192;
  const int lr = lane >> 4, lc = lane & 15;
  int gofs[8];
  #pragma unroll
  for (int i = 0; i < 8; ++i) {
    int r = 4 * i + lr;
    gofs[i] = r * 64 + ((lc ^ (r & 15)) << 2);    // float index within tile
  }
  // read side: lane (q,n) wants global chunk g=4kt+2q+s of row n ->
  // LDS chunk g ^ (n&15). 8 loop-invariant byte offsets.
  int zrd[8];
  #pragma unroll
  for (int kt = 0; kt < 4; ++kt)
    #pragma unroll
    for (int s = 0; s < 2; ++s)
      zrd[2 * kt + s] =
          ZS_BYTE + wave * 8192 + n * 256 + (((4 * kt + 2 * q + s) ^ (n & 15)) << 4);

  // ---- persistent operand fragments, all pinned to the AGPR half ----
  bf16x8 ones;
  #pragma unroll
  for (int i = 0; i < 8; ++i) ones[i] = (__bf16)0.0f;
  if (q == 0) ones[0] = (__bf16)1.0f;
  PIN_AGPR(ones);

  bf16x8 ba1[4], ba2[4], ba3;
  #pragma unroll
  for (int f = 0; f < 4; ++f) {
    ba1[f] = biasA((q == 0) ? sm[SB1 + f * 32 + n] : (__bf16)0.0f);
    ba2[f] = biasA((q == 0) ? sm[SB2 + f * 32 + n] : (__bf16)0.0f);
    PIN_AGPR(ba1[f]); PIN_AGPR(ba2[f]);
  }
  ba3 = biasA((q == 0 && n < 12) ? sm[SB3 + n] : (__bf16)0.0f);
  PIN_AGPR(ba3);

  // persistent zero C-operand (AGPR): every MFMA chain starts from this,
  // eliminating per-tile accumulator zero-init VALU work.
  f32x16 zeroC;
  #pragma unroll
  for (int i = 0; i < 16; ++i) zeroC[i] = 0.0f;
  PIN_AGPR(zeroC);

  const int wid = blockIdx.x * 8 + wave;

  // prologue: async-prefetch first tile's z into this wave's slot.
  {
    const float* zb = z + (long)wid * 2048;
    #pragma unroll
    for (int i = 0; i < 8; ++i) gll16(zb + gofs[i], slotp + (i << 10));
  }

  #pragma unroll 1
  for (int t = wid; t < NTILE; t += WSTRIDE) {
    const long row = (long)t * 32 + n;

    // z(t) landed? (only the 8 gll of tile t are outstanding here; issued a
    // full tile ago -> covered)
    asm volatile("s_waitcnt vmcnt(0)" ::: "memory");

    // x for this tile: issued now so it sits OLDER than gll(t+1) in the vmem
    // queue -> epilogue's x-wait leaves the prefetch outstanding.
    const float* xr = x + row * 9;
    float xv0 = xr[q * 4 + 0], xv1 = xr[q * 4 + 1];
    float xv2 = xr[q * 4 + 2], xv3 = xr[q * 4 + 3];
    float xv4 = xr[8];

    // z tile t: LDS -> regs -> bf16 B-frags (transient, dead after this)
    bf16x8 bz[4];
    #pragma unroll
    for (int kt = 0; kt < 4; ++kt) {
      float4 a = ldz(sm, zrd[2 * kt]);
      float4 b = ldz(sm, zrd[2 * kt + 1]);
      bf16x8 f;
      f[0] = (__bf16)a.x; f[1] = (__bf16)a.y; f[2] = (__bf16)a.z; f[3] = (__bf16)a.w;
      f[4] = (__bf16)b.x; f[5] = (__bf16)b.y; f[6] = (__bf16)b.z; f[7] = (__bf16)b.w;
      bz[kt] = f;
    }
    __builtin_amdgcn_sched_barrier(0);   // reads of slot complete before refill

    // refill slot with tile t+1 (async, no regs; covered by this tile)
    if (t + WSTRIDE < NTILE) {
      const float* zb = z + (long)(t + WSTRIDE) * 2048;
      #pragma unroll
      for (int i = 0; i < 8; ++i) gll16(zb + gofs[i], slotp + (i << 10));
    }
    __builtin_amdgcn_sched_barrier(0);   // gll issue stays here, not sunk

    // ---- layer 1: ft pairs; chains start at bias MFMA (C = zeroC) ----
    bf16x8 bf2[8];
    #pragma unroll
    for (int fp = 0; fp < 2; ++fp) {
      f32x16 aA = MFMA32(ba1[2 * fp + 0], ones, zeroC);
      f32x16 aB = MFMA32(ba1[2 * fp + 1], ones, zeroC);
      PIN_AGPR(aA); PIN_AGPR(aB);
      #pragma unroll
      for (int kt = 0; kt < 4; ++kt) {
        aA = MFMA32(ldw(sm, aw1[kt], SW1 * 2 + (2 * fp + 0) * 4096), bz[kt], aA);
        aB = MFMA32(ldw(sm, aw1[kt], SW1 * 2 + (2 * fp + 1) * 4096), bz[kt], aB);
      }
      #pragma unroll
      for (int i = 0; i < 16; ++i) { aA[i] = fmaxf(aA[i], 0.0f); aB[i] = fmaxf(aB[i], 0.0f); }
      bf2[4 * fp + 0] = mk_bfrag<0>(aA);
      bf2[4 * fp + 1] = mk_bfrag<1>(aA);
      bf2[4 * fp + 2] = mk_bfrag<0>(aB);
      bf2[4 * fp + 3] = mk_bfrag<1>(aB);
    }

    // ---- layer 2 (bias-start chains) with layer 3 fused ----
    f32x16 acc3 = MFMA32(ba3, ones, zeroC);
    PIN_AGPR(acc3);
    #pragma unroll
    for (int fp = 0; fp < 2; ++fp) {
      f32x16 aA = MFMA32(ba2[2 * fp + 0], ones, zeroC);
      f32x16 aB = MFMA32(ba2[2 * fp + 1], ones, zeroC);
      PIN_AGPR(aA); PIN_AGPR(aB);
      #pragma unroll
      for (int kt = 0; kt < 8; ++kt) {
        aA = MFMA32(ldw(sm, aw2[kt & 3], SW2 * 2 + (2 * fp + 0) * 8192 + 128 * (kt >> 2)),
                    bf2[kt], aA);
        aB = MFMA32(ldw(sm, aw2[kt & 3], SW2 * 2 + (2 * fp + 1) * 8192 + 128 * (kt >> 2)),
                    bf2[kt], aB);
      }
      #pragma unroll
      for (int i = 0; i < 16; ++i) { aA[i] = fmaxf(aA[i], 0.0f); aB[i] = fmaxf(aB[i], 0.0f); }
      // h2 features 64*fp + [0,64) == layer-3 K block kt = 4*fp + [0,4)
      acc3 = MFMA32(ldw(sm, aw2[0], SW3 * 2 + 128 * fp), mk_bfrag<0>(aA), acc3);
      acc3 = MFMA32(ldw(sm, aw2[1], SW3 * 2 + 128 * fp), mk_bfrag<1>(aA), acc3);
      acc3 = MFMA32(ldw(sm, aw2[2], SW3 * 2 + 128 * fp), mk_bfrag<0>(aB), acc3);
      acc3 = MFMA32(ldw(sm, aw2[3], SW3 * 2 + 128 * fp), mk_bfrag<1>(aB), acc3);
    }

    // ---- epilogue (only regs 0..7 carry real features) ----
    float t0 = acc3[0], t1 = acc3[1], t2 = acc3[2], t3 = acc3[3];
    float t4 = acc3[4], t5 = acc3[5], t6 = acc3[6], t7 = acc3[7];
    float o0 = 0.f, o1 = 0.f, o2 = 0.f, g1v = 0.f, g2v = 0.f;
    if (q == 0) {
      t0 = fminf(t0, 0.0f); t1 = fminf(t1, 0.0f);
      t2 = fminf(t2, 0.0f); t3 = fminf(t3, 0.0f);
      t4 = fminf(t4, 0.0f);                       // feat 8
      o0 = xv0 * t0 + xv1 * t1 + xv2 * t2 + t5;   // seg0 + I9
      o1 = xv3 * t3 + t6;                         // seg1 part + I10
      o2 = xv4 * t4 + t7;                         // seg2 part + I11
    } else {
      t0 = fminf(t0, 0.0f); t1 = fminf(t1, 0.0f); // feats 4,5
      t3 = fminf(t3, 0.0f);                       // feat 7 (feat 6 passes)
      g1v = xv0 * t0 + xv1 * t1;
      g2v = xv2 * t2 + xv3 * t3;
    }
    float a1v = __shfl_xor(g1v, 32, 64);
    float a2v = __shfl_xor(g2v, 32, 64);
    if (q == 0) {
      float* op = out + row * 3;
      op[0] = o0;
      op[1] = o1 + a1v;
      op[2] = o2 + a2v;
    }
  }
}

extern "C" void kernel_launch(void* const* d_in, const int* in_sizes, int n_in,
                              void* d_out, int out_size, void* d_ws, size_t ws_size,
                              hipStream_t stream) {
  const float* x  = (const float*)d_in[0];
  const float* z  = (const float*)d_in[1];
  const float* W1 = (const float*)d_in[2];
  const float* b1 = (const float*)d_in[3];
  const float* W2 = (const float*)d_in[4];
  const float* b2 = (const float*)d_in[5];
  const float* W3 = (const float*)d_in[6];
  const float* b3 = (const float*)d_in[7];
  tastenet_kernel<<<dim3(NBLK), dim3(NTHR), 0, stream>>>(
      x, z, W1, b1, W2, b2, W3, b3, (float*)d_out);
}